// Round 15
// baseline (630.064 us; speedup 1.0000x reference)
//
#include <hip/hip_runtime.h>

#define TOKENS 8192
#define INF 512
#define HIDDEN 1024
#define NEXP 16

#define AS1 __attribute__((address_space(1)))
#define AS3 __attribute__((address_space(3)))

typedef short bh4 __attribute__((ext_vector_type(4)));
typedef short bh8 __attribute__((ext_vector_type(8)));
typedef float f32x4 __attribute__((ext_vector_type(4)));

__device__ __forceinline__ short f2b(float f) {
  union { float f; unsigned u; } v; v.f = f;
  unsigned r = v.u + 0x7FFFu + ((v.u >> 16) & 1u);
  return (short)(r >> 16);
}
__device__ __forceinline__ float b2f(short h) {
  union { unsigned u; float f; } v; v.u = ((unsigned)(unsigned short)h) << 16;
  return v.f;
}
__device__ __forceinline__ float silu_f(float x) { return x / (1.f + __expf(-x)); }

// MFMA via inline asm; D tied to C with "+v".
__device__ __forceinline__ f32x4 mfma_16x16x32_bf16(bh8 a, bh8 b, f32x4 c) {
  asm("v_mfma_f32_16x16x32_bf16 %0, %1, %2, %0" : "+v"(c) : "v"(a), "v"(b));
  return c;
}

// ---------------- fused prep: convert x + 4 weight transposes + eout zero ----------------
// (round-14 verified, unchanged)
__global__ __launch_bounds__(256) void prep_kernel(
    const float* __restrict__ x, short* __restrict__ xb,
    const float* __restrict__ W1, short* __restrict__ W1t,
    const float* __restrict__ W2, short* __restrict__ W2t,
    const float* __restrict__ Wg1, short* __restrict__ Wg1t,
    const float* __restrict__ Wg2, short* __restrict__ Wg2t,
    float* __restrict__ eout) {
  __shared__ float tile[32][33];
  const int b = blockIdx.x;
  const int tid = threadIdx.x;

  if (b < 1024) {  // convert x -> bf16
    int nv = (TOKENS * INF) >> 2;
    int stride = 1024 * 256;
    for (int i = b * 256 + tid; i < nv; i += stride) {
      float4 v = ((const float4*)x)[i];
      bh4 o;
      o[0] = f2b(v.x); o[1] = f2b(v.y); o[2] = f2b(v.z); o[3] = f2b(v.w);
      *(bh4*)(xb + (size_t)i * 4) = o;
    }
    return;
  }
  if (b >= 27136) {  // zero eout
    int i = (b - 27136) * 256 + tid;
    f32x4 z; z[0] = 0.f; z[1] = 0.f; z[2] = 0.f; z[3] = 0.f;
    *(f32x4*)&eout[(size_t)i * 4] = z;
    return;
  }

  const float* src; short* dst; int R, C, bx, by; bool piDst;
  if (b < 9216) {
    int s = b - 1024; int zz = s >> 9; int rem = s & 511;
    bx = rem & 31; by = rem >> 5; R = INF; C = HIDDEN; piDst = false;
    src = W1 + (size_t)zz * R * C; dst = W1t + (size_t)zz * R * C;
  } else if (b < 25600) {
    int s = b - 9216; int zz = s >> 10; int rem = s & 1023;
    bx = rem & 31; by = rem >> 5; R = HIDDEN; C = HIDDEN; piDst = true;
    src = W2 + (size_t)zz * R * C; dst = W2t + (size_t)zz * R * C;
  } else if (b < 26112) {
    int s = b - 25600; bx = s & 31; by = s >> 5; R = INF; C = HIDDEN; piDst = false;
    src = Wg1; dst = Wg1t;
  } else {
    int s = b - 26112; bx = s & 31; by = s >> 5; R = HIDDEN; C = HIDDEN; piDst = true;
    src = Wg2; dst = Wg2t;
  }
  const int c0 = bx * 32, r0 = by * 32;
  {
    const int row = tid >> 3, col4 = (tid & 7) * 4;
    float4 v = *(const float4*)&src[(size_t)(r0 + row) * C + (c0 + col4)];
    tile[row][col4 + 0] = v.x; tile[row][col4 + 1] = v.y;
    tile[row][col4 + 2] = v.z; tile[row][col4 + 3] = v.w;
  }
  __syncthreads();
  {
    const int dc = tid >> 3, g = tid & 7;
    bh4 o;
    o[0] = f2b(tile[4 * g + 0][dc]); o[1] = f2b(tile[4 * g + 1][dc]);
    o[2] = f2b(tile[4 * g + 2][dc]); o[3] = f2b(tile[4 * g + 3][dc]);
    const int base = piDst ? ((g & 3) * 8 + (g >> 2) * 4) : (4 * g);
    *(bh4*)&dst[(size_t)(c0 + dc) * R + r0 + base] = o;
  }
}

// ---------------- 128x128-tile bf16 MFMA GEMM, BK=32 double-buffered ----------------
// T3-minimum 2-phase schedule at UNCHANGED LDS footprint (2 bufs x 16KB = 32KB):
//   per K-tile: {stage t+1 into buf^1} -> {ds_read + 16 MFMA on buf} -> barrier
// One barrier/tile (its implicit vmcnt(0) drain lands after the covering MFMA
// work instead of right after issue). Swizzle for BK=32 rows (64B): col-group
// (4x8 elems) XOR'd with row&3; read granule (4*(l15&1) + quad^(l15&3)) mod 8
// is uniform 8 lanes/granule -> conflict-free. Same per-lane k-bijection for
// A and B; k-accumulation order identical to round 14 -> bit-identical output.
// Everything else (swapped-operand D layout, M-strip XCD remap, LB(256,4),
// pi'd h1/W2t basis) verified rounds 6-14.
__global__ __launch_bounds__(256, 4) void gemm_moe(
    const short* __restrict__ Abase, size_t aStride,
    const short* __restrict__ BtE, const short* __restrict__ BtG, size_t bStride,
    const float* __restrict__ biasE, const float* __restrict__ biasG,
    short* __restrict__ Cbase, size_t cStride,
    const float* __restrict__ W3all, float* __restrict__ eout,
    int jobBase, int K, int phase) {
  __shared__ short As[2][128][32];   // 2 x 8KB
  __shared__ short Bs[2][128][32];   // 2 x 8KB
  const int z = blockIdx.z;
  const int job = jobBase + z;
  const short* A = Abase + (size_t)z * aStride;
  const short* Bt = (job < NEXP) ? BtE + (size_t)job * bStride : BtG;
  const float* bias = (job < NEXP) ? biasE + (size_t)job * HIDDEN : biasG;

  const int bx = blockIdx.x, by = blockIdx.y;
  const int n0 = (by >> 3) * 128;
  const int m0 = (bx * 8 + (by & 7)) * 128;

  const int tid = threadIdx.x;
  const int lane = tid & 63;
  const int wid = tid >> 6;           // 0..3
  const int wm = (wid >> 1) * 64;
  const int wn = (wid & 1) * 64;
  const int quad = lane >> 4;
  const int l15 = lane & 15;

  f32x4 acc[4][4];
  #pragma unroll
  for (int i = 0; i < 4; ++i)
    #pragma unroll
    for (int j = 0; j < 4; ++j) {
      acc[i][j][0] = 0.f; acc[i][j][1] = 0.f; acc[i][j][2] = 0.f; acc[i][j][3] = 0.f;
    }

  // staging geometry: 8 gload_lds/tile (4 A + 4 B across 4 waves; 2+2 per wave).
  // instr (wid,i) covers rows 32*wid+16*i .. +16; lane -> row +(lane>>2),
  // physical col-group lane&3 holding logical group (lane&3)^(row&3).
  const int srow = lane >> 2;                              // 0..15
  const int sg = ((lane & 3) ^ (srow & 3)) << 3;           // pre-swizzled src col
  const short* aB = A + (size_t)(m0 + wid * 32 + srow) * K + sg;
  const short* bB = Bt + (size_t)(n0 + wid * 32 + srow) * K + sg;
  char* ldsA = (char*)&As[0][0][0];
  char* ldsB = (char*)&Bs[0][0][0];
  const int dOff = (wid * 2) * 1024 + lane * 16;           // + i*1024 + buf*8192

  const int nkt = K >> 5;

  // prologue: stage tile 0 -> buf 0
  #pragma unroll
  for (int i = 0; i < 2; ++i) {
    __builtin_amdgcn_global_load_lds(
        (const AS1 void*)(aB + (size_t)(16 * i) * K),
        (AS3 void*)(ldsA + dOff + i * 1024), 16, 0, 0);
    __builtin_amdgcn_global_load_lds(
        (const AS1 void*)(bB + (size_t)(16 * i) * K),
        (AS3 void*)(ldsB + dOff + i * 1024), 16, 0, 0);
  }
  __syncthreads();

  const int pg = (quad ^ (l15 & 3)) << 3;  // read-side physical col (elems)
  int buf = 0;
  for (int t = 0; t < nkt; ++t) {
    // stage t+1 into buf^1 (issued before compute; drains at the barrier)
    if (t + 1 < nkt) {
      const int ktn = (t + 1) << 5;
      const int dB = (buf ^ 1) * 8192 + dOff;
      #pragma unroll
      for (int i = 0; i < 2; ++i) {
        __builtin_amdgcn_global_load_lds(
            (const AS1 void*)(aB + (size_t)(16 * i) * K + ktn),
            (AS3 void*)(ldsA + dB + i * 1024), 16, 0, 0);
        __builtin_amdgcn_global_load_lds(
            (const AS1 void*)(bB + (size_t)(16 * i) * K + ktn),
            (AS3 void*)(ldsB + dB + i * 1024), 16, 0, 0);
      }
    }
    // compute on buf
    bh8 af[4], bfr[4];
    #pragma unroll
    for (int mi = 0; mi < 4; ++mi)
      af[mi] = *(const bh8*)&As[buf][wm + mi * 16 + l15][pg];
    #pragma unroll
    for (int ni = 0; ni < 4; ++ni)
      bfr[ni] = *(const bh8*)&Bs[buf][wn + ni * 16 + l15][pg];
    #pragma unroll
    for (int mi = 0; mi < 4; ++mi)
      #pragma unroll
      for (int ni = 0; ni < 4; ++ni)
        acc[mi][ni] = mfma_16x16x32_bf16(bfr[ni], af[mi], acc[mi][ni]);
    __syncthreads();  // drains stage (vmcnt) + fences buf reads; 1 barrier/tile
    buf ^= 1;
  }

  // ---- Epilogues. Swapped D layout: m = l15, n = quad*4 + r (verified r6-r14) ----
  if (phase == 1) {
    short* C = Cbase + (size_t)z * cStride;
    f32x4 bv4[4];
    #pragma unroll
    for (int ni = 0; ni < 4; ++ni)
      bv4[ni] = *(const f32x4*)&bias[n0 + wn + ni * 16 + quad * 4];
    #pragma unroll
    for (int mi = 0; mi < 4; ++mi) {
      int mrow = m0 + wm + mi * 16 + l15;
      #pragma unroll
      for (int blk = 0; blk < 2; ++blk) {
        bh8 o;
        #pragma unroll
        for (int r = 0; r < 4; ++r) {
          o[r]     = f2b(silu_f(acc[mi][blk * 2 + 0][r] + bv4[blk * 2 + 0][r]));
          o[r + 4] = f2b(silu_f(acc[mi][blk * 2 + 1][r] + bv4[blk * 2 + 1][r]));
        }
        *(bh8*)&C[(size_t)mrow * HIDDEN + n0 + wn + blk * 32 + quad * 8] = o;
      }
    }
  } else if (job == NEXP) {
    short* C = Cbase;
    #pragma unroll
    for (int ni = 0; ni < 4; ++ni) {
      int nb = wn + ni * 16 + quad * 4;
      float4 bv4 = *(const float4*)&bias[n0 + nb];
      #pragma unroll
      for (int mi = 0; mi < 4; ++mi) {
        int mrow = m0 + wm + mi * 16 + l15;
        bh4 o;
        o[0] = f2b(silu_f(acc[mi][ni][0] + bv4.x));
        o[1] = f2b(silu_f(acc[mi][ni][1] + bv4.y));
        o[2] = f2b(silu_f(acc[mi][ni][2] + bv4.z));
        o[3] = f2b(silu_f(acc[mi][ni][3] + bv4.w));
        *(bh4*)&C[(size_t)mrow * HIDDEN + n0 + nb] = o;
      }
    }
  } else {
    const float* w3 = W3all + (size_t)job * HIDDEN;
    float4 bv4[4], wv4[4];
    #pragma unroll
    for (int ni = 0; ni < 4; ++ni) {
      int nb = n0 + wn + ni * 16 + quad * 4;
      bv4[ni] = *(const float4*)&bias[nb];
      wv4[ni] = *(const float4*)&w3[nb];
    }
    #pragma unroll
    for (int mi = 0; mi < 4; ++mi) {
      float s = 0.f;
      #pragma unroll
      for (int ni = 0; ni < 4; ++ni) {
        s += silu_f(acc[mi][ni][0] + bv4[ni].x) * wv4[ni].x;
        s += silu_f(acc[mi][ni][1] + bv4[ni].y) * wv4[ni].y;
        s += silu_f(acc[mi][ni][2] + bv4[ni].z) * wv4[ni].z;
        s += silu_f(acc[mi][ni][3] + bv4[ni].w) * wv4[ni].w;
      }
      s += __shfl_xor(s, 16);
      s += __shfl_xor(s, 32);
      if (quad == 0) {
        int mrow = m0 + wm + mi * 16 + l15;
        atomicAdd(&eout[(size_t)mrow * NEXP + job], s);
      }
    }
  }
}

// ---------------- gating logits + softmax + final mix (round-12 verified) ----------------
__global__ __launch_bounds__(256) void final_kernel(
    const short* __restrict__ g2b, const float* __restrict__ Wg3,
    const float* __restrict__ bg3, const float* __restrict__ eout,
    const float* __restrict__ b3, float* __restrict__ out) {
  int wave = (blockIdx.x * 256 + threadIdx.x) >> 6;
  int lane = threadIdx.x & 63;
  int r0 = wave * 4;
  float lp[4][16];
  #pragma unroll
  for (int r = 0; r < 4; ++r)
    #pragma unroll
    for (int j = 0; j < 16; ++j) lp[r][j] = 0.f;

  for (int t = 0; t < HIDDEN / 64; ++t) {
    int k = t * 64 + lane;
    float g0 = b2f(g2b[(size_t)(r0 + 0) * HIDDEN + k]);
    float g1 = b2f(g2b[(size_t)(r0 + 1) * HIDDEN + k]);
    float g2 = b2f(g2b[(size_t)(r0 + 2) * HIDDEN + k]);
    float g3 = b2f(g2b[(size_t)(r0 + 3) * HIDDEN + k]);
    const float4* wr4 = (const float4*)(Wg3 + (size_t)k * NEXP);
    float4 wa = wr4[0], wb = wr4[1], wc = wr4[2], wd = wr4[3];
    float w[16] = {wa.x, wa.y, wa.z, wa.w, wb.x, wb.y, wb.z, wb.w,
                   wc.x, wc.y, wc.z, wc.w, wd.x, wd.y, wd.z, wd.w};
    #pragma unroll
    for (int j = 0; j < 16; ++j) {
      lp[0][j] = fmaf(g0, w[j], lp[0][j]);
      lp[1][j] = fmaf(g1, w[j], lp[1][j]);
      lp[2][j] = fmaf(g2, w[j], lp[2][j]);
      lp[3][j] = fmaf(g3, w[j], lp[3][j]);
    }
  }
  #pragma unroll
  for (int r = 0; r < 4; ++r) {
    int row = r0 + r;
    float lpr[16];
    #pragma unroll
    for (int j = 0; j < 16; ++j) {
      float v = lp[r][j];
      v += __shfl_xor(v, 1);  v += __shfl_xor(v, 2);  v += __shfl_xor(v, 4);
      v += __shfl_xor(v, 8);  v += __shfl_xor(v, 16); v += __shfl_xor(v, 32);
      lpr[j] = v + bg3[j];
    }
    float mx = lpr[0];
    #pragma unroll
    for (int j = 1; j < 16; ++j) mx = fmaxf(mx, lpr[j]);
    float s = 0.f, accv = 0.f;
    #pragma unroll
    for (int j = 0; j < 16; ++j) {
      float p = __expf(lpr[j] - mx);
      s += p;
      accv = fmaf(p, eout[(size_t)row * NEXP + j] + b3[j], accv);
    }
    if (lane == 0) out[row] = accv / s;
  }
}

extern "C" void kernel_launch(void* const* d_in, const int* in_sizes, int n_in,
                              void* d_out, int out_size, void* d_ws, size_t ws_size,
                              hipStream_t stream) {
  const float* x   = (const float*)d_in[0];
  const float* W1  = (const float*)d_in[1];
  const float* b1  = (const float*)d_in[2];
  const float* W2  = (const float*)d_in[3];
  const float* b2  = (const float*)d_in[4];
  const float* W3  = (const float*)d_in[5];
  const float* b3  = (const float*)d_in[6];
  const float* Wg1 = (const float*)d_in[7];
  const float* bg1 = (const float*)d_in[8];
  const float* Wg2 = (const float*)d_in[9];
  const float* bg2 = (const float*)d_in[10];
  const float* Wg3 = (const float*)d_in[11];
  const float* bg3 = (const float*)d_in[12];
  float* out = (float*)d_out;

  char* p = (char*)d_ws;
  short* xb   = (short*)p; p += (size_t)TOKENS * INF * 2;
  short* W1t  = (short*)p; p += (size_t)NEXP * HIDDEN * INF * 2;
  short* W2t  = (short*)p; p += (size_t)NEXP * HIDDEN * HIDDEN * 2;
  short* Wg1t = (short*)p; p += (size_t)HIDDEN * INF * 2;
  short* Wg2t = (short*)p; p += (size_t)HIDDEN * HIDDEN * 2;
  short* g2b  = (short*)p; p += (size_t)TOKENS * HIDDEN * 2;
  float* eout = (float*)p; p += (size_t)TOKENS * NEXP * 4;
  size_t fixedBytes = (size_t)(p - (char*)d_ws);
  short* h1slab = (short*)p;
  const size_t SLOT_ELEMS = (size_t)TOKENS * HIDDEN;
  const size_t SLOT_BYTES = SLOT_ELEMS * 2;          // 16 MB
  size_t avail = ws_size > fixedBytes ? ws_size - fixedBytes : 0;
  int slots = (int)(avail / SLOT_BYTES);
  if (slots > NEXP + 1) slots = NEXP + 1;
  if (slots < 1) slots = 1;

  // fused convert + transposes + eout zero (27264 blocks)
  prep_kernel<<<27264, 256, 0, stream>>>(x, xb, W1, W1t, W2, W2t, Wg1, Wg1t,
                                         Wg2, Wg2t, eout);

  for (int base = 0; base < NEXP + 1; base += slots) {
    int cnt = NEXP + 1 - base;
    if (cnt > slots) cnt = slots;
    dim3 gg(HIDDEN / 128, TOKENS / 128, cnt);  // (8, 64, cnt)
    gemm_moe<<<gg, 256, 0, stream>>>(xb, 0, W1t, Wg1t, (size_t)INF * HIDDEN,
                                     b1, bg1, h1slab, SLOT_ELEMS,
                                     nullptr, nullptr, base, INF, 1);
    gemm_moe<<<gg, 256, 0, stream>>>(h1slab, SLOT_ELEMS, W2t, Wg2t, (size_t)HIDDEN * HIDDEN,
                                     b2, bg2, g2b, 0,
                                     W3, eout, base, HIDDEN, 2);
  }

  // 512 blocks x 4 waves x 4 rows = 8192 rows
  final_kernel<<<TOKENS / 16, 256, 0, stream>>>(g2b, Wg3, bg3, eout, b3, out);
}

// Round 16
// 528.585 us; speedup vs baseline: 1.1920x; 1.1920x over previous
//
#include <hip/hip_runtime.h>

#define TOKENS 8192
#define INF 512
#define HIDDEN 1024
#define NEXP 16

typedef short bh4 __attribute__((ext_vector_type(4)));
typedef short bh8 __attribute__((ext_vector_type(8)));
typedef float f32x4 __attribute__((ext_vector_type(4)));

__device__ __forceinline__ short f2b(float f) {
  union { float f; unsigned u; } v; v.f = f;
  unsigned r = v.u + 0x7FFFu + ((v.u >> 16) & 1u);
  return (short)(r >> 16);
}
__device__ __forceinline__ float b2f(short h) {
  union { unsigned u; float f; } v; v.u = ((unsigned)(unsigned short)h) << 16;
  return v.f;
}
__device__ __forceinline__ float silu_f(float x) { return x / (1.f + __expf(-x)); }

// MFMA via inline asm; D tied to C with "+v".
__device__ __forceinline__ f32x4 mfma_16x16x32_bf16(bh8 a, bh8 b, f32x4 c) {
  asm("v_mfma_f32_16x16x32_bf16 %0, %1, %2, %0" : "+v"(c) : "v"(a), "v"(b));
  return c;
}

// ---------------- fused prep: convert x + 4 weight transposes + eout zero ----------------
// ranges: [0,1024) convert; [1024,9216) W1t; [9216,25600) W2t (pi'd k-cols);
//         [25600,26112) Wg1t; [26112,27136) Wg2t (pi'd); [27136,27264) eout=0.
// Transpose: 32x32 fp32 tile; each thread 1x float4 load + 1x bh4 store.
// pi (h1/W2t k-col permutation, verified round 13): pi32(4g+k) = (g&3)*8+(g>>2)*4+k
// -> bh4 stores stay contiguous; only the base is remapped.
__global__ __launch_bounds__(256) void prep_kernel(
    const float* __restrict__ x, short* __restrict__ xb,
    const float* __restrict__ W1, short* __restrict__ W1t,
    const float* __restrict__ W2, short* __restrict__ W2t,
    const float* __restrict__ Wg1, short* __restrict__ Wg1t,
    const float* __restrict__ Wg2, short* __restrict__ Wg2t,
    float* __restrict__ eout) {
  __shared__ float tile[32][33];
  const int b = blockIdx.x;
  const int tid = threadIdx.x;

  if (b < 1024) {  // convert x -> bf16
    int nv = (TOKENS * INF) >> 2;
    int stride = 1024 * 256;
    for (int i = b * 256 + tid; i < nv; i += stride) {
      float4 v = ((const float4*)x)[i];
      bh4 o;
      o[0] = f2b(v.x); o[1] = f2b(v.y); o[2] = f2b(v.z); o[3] = f2b(v.w);
      *(bh4*)(xb + (size_t)i * 4) = o;
    }
    return;
  }
  if (b >= 27136) {  // zero eout (128 blocks x 256 threads x 16B = 512KB)
    int i = (b - 27136) * 256 + tid;
    f32x4 z; z[0] = 0.f; z[1] = 0.f; z[2] = 0.f; z[3] = 0.f;
    *(f32x4*)&eout[(size_t)i * 4] = z;
    return;
  }

  const float* src; short* dst; int R, C, bx, by; bool piDst;
  if (b < 9216) {          // W1: [16][512][1024] -> [16][1024][512]
    int s = b - 1024; int zz = s >> 9; int rem = s & 511;
    bx = rem & 31; by = rem >> 5; R = INF; C = HIDDEN; piDst = false;
    src = W1 + (size_t)zz * R * C; dst = W1t + (size_t)zz * R * C;
  } else if (b < 25600) {  // W2: [16][1024][1024] -> transposed, pi'd k
    int s = b - 9216; int zz = s >> 10; int rem = s & 1023;
    bx = rem & 31; by = rem >> 5; R = HIDDEN; C = HIDDEN; piDst = true;
    src = W2 + (size_t)zz * R * C; dst = W2t + (size_t)zz * R * C;
  } else if (b < 26112) {  // Wg1: [512][1024]
    int s = b - 25600; bx = s & 31; by = s >> 5; R = INF; C = HIDDEN; piDst = false;
    src = Wg1; dst = Wg1t;
  } else {                 // Wg2: [1024][1024], pi'd k
    int s = b - 26112; bx = s & 31; by = s >> 5; R = HIDDEN; C = HIDDEN; piDst = true;
    src = Wg2; dst = Wg2t;
  }
  const int c0 = bx * 32, r0 = by * 32;
  // load: row = tid>>3, cols col4..col4+3 (one float4)
  {
    const int row = tid >> 3, col4 = (tid & 7) * 4;
    float4 v = *(const float4*)&src[(size_t)(r0 + row) * C + (c0 + col4)];
    tile[row][col4 + 0] = v.x; tile[row][col4 + 1] = v.y;
    tile[row][col4 + 2] = v.z; tile[row][col4 + 3] = v.w;
  }
  __syncthreads();
  // store: dst row c0+dc gets source rows r0+4g..r0+4g+3 as one bh4
  {
    const int dc = tid >> 3, g = tid & 7;
    bh4 o;
    o[0] = f2b(tile[4 * g + 0][dc]); o[1] = f2b(tile[4 * g + 1][dc]);
    o[2] = f2b(tile[4 * g + 2][dc]); o[3] = f2b(tile[4 * g + 3][dc]);
    const int base = piDst ? ((g & 3) * 8 + (g >> 2) * 4) : (4 * g);
    *(bh4*)&dst[(size_t)(c0 + dc) * R + r0 + base] = o;
  }
}

// ---------------- 128x128-tile bf16 MFMA GEMM, z-batched over 17 jobs ----------------
// Round-14 verified kernel, unchanged. (16x16x32, swapped operands -> D: m=l15,
// n=quad*4+r; XOR-swizzled LDS both-sides [slot = quad ^ (row&7), the ONLY
// pattern measured conflict-free]; M-strip XCD remap; LB(256,4): 64 arch VGPR +
// 64 AGPR acc = 128 -> 4 waves/SIMD; pi-permuted h1 layout with pi'd W2t/Wg2t.
// Closed structural paths (measured): 8-phase (r4 -14%), 256-tile (r7 fail),
// 32x32 MFMA (r10 +2.3e7 conflicts), BK=32 dbuf (r15 +2.3e7 conflicts).
__global__ __launch_bounds__(256, 4) void gemm_moe(
    const short* __restrict__ Abase, size_t aStride,
    const short* __restrict__ BtE, const short* __restrict__ BtG, size_t bStride,
    const float* __restrict__ biasE, const float* __restrict__ biasG,
    short* __restrict__ Cbase, size_t cStride,
    const float* __restrict__ W3all, float* __restrict__ eout,
    int jobBase, int K, int phase) {
  __shared__ short As[128][64];
  __shared__ short Bs[128][64];
  const int z = blockIdx.z;
  const int job = jobBase + z;
  const short* A = Abase + (size_t)z * aStride;
  const short* Bt = (job < NEXP) ? BtE + (size_t)job * bStride : BtG;
  const float* bias = (job < NEXP) ? biasE + (size_t)job * HIDDEN : biasG;

  const int bx = blockIdx.x, by = blockIdx.y;
  const int n0 = (by >> 3) * 128;
  const int m0 = (bx * 8 + (by & 7)) * 128;

  const int tid = threadIdx.x;
  const int lane = tid & 63;
  const int wid = tid >> 6;           // 0..3
  const int wm = (wid >> 1) * 64;
  const int wn = (wid & 1) * 64;
  const int quad = lane >> 4;
  const int l15 = lane & 15;

  f32x4 acc[4][4];
  #pragma unroll
  for (int i = 0; i < 4; ++i)
    #pragma unroll
    for (int j = 0; j < 4; ++j) {
      acc[i][j][0] = 0.f; acc[i][j][1] = 0.f; acc[i][j][2] = 0.f; acc[i][j][3] = 0.f;
    }

  const int srow = lane >> 3;                         // 0..7
  const int scol = ((lane & 7) << 3) ^ (srow << 3);   // pre-swizzled source col
  const short* aBase = A + (size_t)(m0 + wid * 32 + srow) * K + scol;
  const short* bBase = Bt + (size_t)(n0 + wid * 32 + srow) * K + scol;
  char* ldsA = (char*)&As[0][0];
  char* ldsB = (char*)&Bs[0][0];

  for (int kt = 0; kt < K; kt += 64) {
    __syncthreads();
    #pragma unroll
    for (int i = 0; i < 4; ++i) {
      __builtin_amdgcn_global_load_lds(
          (const __attribute__((address_space(1))) void*)(aBase + (size_t)(i * 8) * K + kt),
          (__attribute__((address_space(3))) void*)(ldsA + (wid * 4 + i) * 1024), 16, 0, 0);
      __builtin_amdgcn_global_load_lds(
          (const __attribute__((address_space(1))) void*)(bBase + (size_t)(i * 8) * K + kt),
          (__attribute__((address_space(3))) void*)(ldsB + (wid * 4 + i) * 1024), 16, 0, 0);
    }
    __syncthreads();

    #pragma unroll
    for (int ks = 0; ks < 2; ++ks) {
      bh8 af[4], bfr[4];
      #pragma unroll
      for (int mi = 0; mi < 4; ++mi) {
        int row = wm + mi * 16 + l15;
        int col = ((ks << 5) + (quad << 3)) ^ ((row & 7) << 3);
        af[mi] = *(const bh8*)&As[row][col];
      }
      #pragma unroll
      for (int ni = 0; ni < 4; ++ni) {
        int row = wn + ni * 16 + l15;
        int col = ((ks << 5) + (quad << 3)) ^ ((row & 7) << 3);
        bfr[ni] = *(const bh8*)&Bs[row][col];
      }
      // swapped operands: D layout m = l15, n = quad*4 + r
      #pragma unroll
      for (int mi = 0; mi < 4; ++mi)
        #pragma unroll
        for (int ni = 0; ni < 4; ++ni)
          acc[mi][ni] = mfma_16x16x32_bf16(bfr[ni], af[mi], acc[mi][ni]);
    }
  }

  // ---- Epilogues. Swapped D layout: m = l15, n = quad*4 + r ----
  if (phase == 1) {
    // pi-permuted h1 store: 8x 16B full-line-covering stores (verified r13)
    short* C = Cbase + (size_t)z * cStride;
    f32x4 bv4[4];
    #pragma unroll
    for (int ni = 0; ni < 4; ++ni)
      bv4[ni] = *(const f32x4*)&bias[n0 + wn + ni * 16 + quad * 4];
    #pragma unroll
    for (int mi = 0; mi < 4; ++mi) {
      int mrow = m0 + wm + mi * 16 + l15;
      #pragma unroll
      for (int blk = 0; blk < 2; ++blk) {
        bh8 o;
        #pragma unroll
        for (int r = 0; r < 4; ++r) {
          o[r]     = f2b(silu_f(acc[mi][blk * 2 + 0][r] + bv4[blk * 2 + 0][r]));
          o[r + 4] = f2b(silu_f(acc[mi][blk * 2 + 1][r] + bv4[blk * 2 + 1][r]));
        }
        *(bh8*)&C[(size_t)mrow * HIDDEN + n0 + wn + blk * 32 + quad * 8] = o;
      }
    }
  } else if (job == NEXP) {
    // gating layer-2 output g2b: logical layout (final_kernel reads it directly)
    short* C = Cbase;
    #pragma unroll
    for (int ni = 0; ni < 4; ++ni) {
      int nb = wn + ni * 16 + quad * 4;
      float4 bv4 = *(const float4*)&bias[n0 + nb];
      #pragma unroll
      for (int mi = 0; mi < 4; ++mi) {
        int mrow = m0 + wm + mi * 16 + l15;
        bh4 o;
        o[0] = f2b(silu_f(acc[mi][ni][0] + bv4.x));
        o[1] = f2b(silu_f(acc[mi][ni][1] + bv4.y));
        o[2] = f2b(silu_f(acc[mi][ni][2] + bv4.z));
        o[3] = f2b(silu_f(acc[mi][ni][3] + bv4.w));
        *(bh4*)&C[(size_t)mrow * HIDDEN + n0 + nb] = o;
      }
    }
  } else {
    const float* w3 = W3all + (size_t)job * HIDDEN;
    float4 bv4[4], wv4[4];
    #pragma unroll
    for (int ni = 0; ni < 4; ++ni) {
      int nb = n0 + wn + ni * 16 + quad * 4;
      bv4[ni] = *(const float4*)&bias[nb];
      wv4[ni] = *(const float4*)&w3[nb];
    }
    #pragma unroll
    for (int mi = 0; mi < 4; ++mi) {
      float s = 0.f;
      #pragma unroll
      for (int ni = 0; ni < 4; ++ni) {
        s += silu_f(acc[mi][ni][0] + bv4[ni].x) * wv4[ni].x;
        s += silu_f(acc[mi][ni][1] + bv4[ni].y) * wv4[ni].y;
        s += silu_f(acc[mi][ni][2] + bv4[ni].z) * wv4[ni].z;
        s += silu_f(acc[mi][ni][3] + bv4[ni].w) * wv4[ni].w;
      }
      s += __shfl_xor(s, 16);
      s += __shfl_xor(s, 32);
      if (quad == 0) {
        int mrow = m0 + wm + mi * 16 + l15;
        atomicAdd(&eout[(size_t)mrow * NEXP + job], s);
      }
    }
  }
}

// ---------------- gating logits + softmax + final mix ----------------
// 4 rows per wave; grid = TOKENS/16 blocks (4 waves x 4 rows per block).
__global__ __launch_bounds__(256) void final_kernel(
    const short* __restrict__ g2b, const float* __restrict__ Wg3,
    const float* __restrict__ bg3, const float* __restrict__ eout,
    const float* __restrict__ b3, float* __restrict__ out) {
  int wave = (blockIdx.x * 256 + threadIdx.x) >> 6;
  int lane = threadIdx.x & 63;
  int r0 = wave * 4;
  float lp[4][16];
  #pragma unroll
  for (int r = 0; r < 4; ++r)
    #pragma unroll
    for (int j = 0; j < 16; ++j) lp[r][j] = 0.f;

  for (int t = 0; t < HIDDEN / 64; ++t) {
    int k = t * 64 + lane;
    float g0 = b2f(g2b[(size_t)(r0 + 0) * HIDDEN + k]);
    float g1 = b2f(g2b[(size_t)(r0 + 1) * HIDDEN + k]);
    float g2 = b2f(g2b[(size_t)(r0 + 2) * HIDDEN + k]);
    float g3 = b2f(g2b[(size_t)(r0 + 3) * HIDDEN + k]);
    const float4* wr4 = (const float4*)(Wg3 + (size_t)k * NEXP);
    float4 wa = wr4[0], wb = wr4[1], wc = wr4[2], wd = wr4[3];
    float w[16] = {wa.x, wa.y, wa.z, wa.w, wb.x, wb.y, wb.z, wb.w,
                   wc.x, wc.y, wc.z, wc.w, wd.x, wd.y, wd.z, wd.w};
    #pragma unroll
    for (int j = 0; j < 16; ++j) {
      lp[0][j] = fmaf(g0, w[j], lp[0][j]);
      lp[1][j] = fmaf(g1, w[j], lp[1][j]);
      lp[2][j] = fmaf(g2, w[j], lp[2][j]);
      lp[3][j] = fmaf(g3, w[j], lp[3][j]);
    }
  }
  #pragma unroll
  for (int r = 0; r < 4; ++r) {
    int row = r0 + r;
    float lpr[16];
    #pragma unroll
    for (int j = 0; j < 16; ++j) {
      float v = lp[r][j];
      v += __shfl_xor(v, 1);  v += __shfl_xor(v, 2);  v += __shfl_xor(v, 4);
      v += __shfl_xor(v, 8);  v += __shfl_xor(v, 16); v += __shfl_xor(v, 32);
      lpr[j] = v + bg3[j];
    }
    float mx = lpr[0];
    #pragma unroll
    for (int j = 1; j < 16; ++j) mx = fmaxf(mx, lpr[j]);
    float s = 0.f, accv = 0.f;
    #pragma unroll
    for (int j = 0; j < 16; ++j) {
      float p = __expf(lpr[j] - mx);
      s += p;
      accv = fmaf(p, eout[(size_t)row * NEXP + j] + b3[j], accv);
    }
    if (lane == 0) out[row] = accv / s;
  }
}

extern "C" void kernel_launch(void* const* d_in, const int* in_sizes, int n_in,
                              void* d_out, int out_size, void* d_ws, size_t ws_size,
                              hipStream_t stream) {
  const float* x   = (const float*)d_in[0];
  const float* W1  = (const float*)d_in[1];
  const float* b1  = (const float*)d_in[2];
  const float* W2  = (const float*)d_in[3];
  const float* b2  = (const float*)d_in[4];
  const float* W3  = (const float*)d_in[5];
  const float* b3  = (const float*)d_in[6];
  const float* Wg1 = (const float*)d_in[7];
  const float* bg1 = (const float*)d_in[8];
  const float* Wg2 = (const float*)d_in[9];
  const float* bg2 = (const float*)d_in[10];
  const float* Wg3 = (const float*)d_in[11];
  const float* bg3 = (const float*)d_in[12];
  float* out = (float*)d_out;

  // workspace layout: fixed region (~75.5 MB) + h1 slab (17 x 16MB slots if ws allows)
  char* p = (char*)d_ws;
  short* xb   = (short*)p; p += (size_t)TOKENS * INF * 2;
  short* W1t  = (short*)p; p += (size_t)NEXP * HIDDEN * INF * 2;
  short* W2t  = (short*)p; p += (size_t)NEXP * HIDDEN * HIDDEN * 2;
  short* Wg1t = (short*)p; p += (size_t)HIDDEN * INF * 2;
  short* Wg2t = (short*)p; p += (size_t)HIDDEN * HIDDEN * 2;
  short* g2b  = (short*)p; p += (size_t)TOKENS * HIDDEN * 2;
  float* eout = (float*)p; p += (size_t)TOKENS * NEXP * 4;
  size_t fixedBytes = (size_t)(p - (char*)d_ws);
  short* h1slab = (short*)p;
  const size_t SLOT_ELEMS = (size_t)TOKENS * HIDDEN;
  const size_t SLOT_BYTES = SLOT_ELEMS * 2;          // 16 MB
  size_t avail = ws_size > fixedBytes ? ws_size - fixedBytes : 0;
  int slots = (int)(avail / SLOT_BYTES);
  if (slots > NEXP + 1) slots = NEXP + 1;
  if (slots < 1) slots = 1;

  // fused convert + transposes + eout zero (27264 blocks)
  prep_kernel<<<27264, 256, 0, stream>>>(x, xb, W1, W1t, W2, W2t, Wg1, Wg1t,
                                         Wg2, Wg2t, eout);

  // 17 jobs: experts 0..15 + gating (job 16), processed in groups of `slots`
  for (int base = 0; base < NEXP + 1; base += slots) {
    int cnt = NEXP + 1 - base;
    if (cnt > slots) cnt = slots;
    dim3 gg(HIDDEN / 128, TOKENS / 128, cnt);  // (8, 64, cnt)
    // layer 1: A = xb (shared), C = h1p slab slot z (pi-permuted cols)
    gemm_moe<<<gg, 256, 0, stream>>>(xb, 0, W1t, Wg1t, (size_t)INF * HIDDEN,
                                     b1, bg1, h1slab, SLOT_ELEMS,
                                     nullptr, nullptr, base, INF, 1);
    // layer 2: A = h1p slot z; experts reduce into eout, gating writes g2b
    gemm_moe<<<gg, 256, 0, stream>>>(h1slab, SLOT_ELEMS, W2t, Wg2t, (size_t)HIDDEN * HIDDEN,
                                     b2, bg2, g2b, 0,
                                     W3, eout, base, HIDDEN, 2);
  }

  // 512 blocks x 4 waves x 4 rows = 8192 rows
  final_kernel<<<TOKENS / 16, 256, 0, stream>>>(g2b, Wg3, bg3, eout, b3, out);
}